// Round 1
// baseline (719.201 us; speedup 1.0000x reference)
//
#include <hip/hip_runtime.h>
#include <hip/hip_bf16.h>

#define NVEC   262144
#define NLIST  1024
#define DIM    64

// ---------------------------------------------------------------------------
// Kernel 1: per-centroid squared norm -> ws
// ---------------------------------------------------------------------------
__global__ __launch_bounds__(256) void csq_kernel(const float* __restrict__ cents,
                                                  float* __restrict__ csq) {
    int c = blockIdx.x * blockDim.x + threadIdx.x;
    if (c >= NLIST) return;
    const float4* p = (const float4*)(cents + (size_t)c * DIM);
    float s = 0.f;
#pragma unroll
    for (int i = 0; i < DIM / 4; ++i) {
        float4 t = p[i];
        s += t.x * t.x + t.y * t.y + t.z * t.z + t.w * t.w;
    }
    csq[c] = s;
}

// ---------------------------------------------------------------------------
// Kernel 2: argmin over centroids of (csq[c] - 2 * x.c)
// One thread per vector; vector held in 64 VGPRs. Centroid reads are
// wave-uniform -> scalar loads (s_load), so the VALU only does FMAs.
// ---------------------------------------------------------------------------
__global__ __launch_bounds__(256) void assign_kernel(const float* __restrict__ vecs,
                                                     const float* __restrict__ cents,
                                                     const float* __restrict__ csq,
                                                     int* __restrict__ assign) {
    int v = blockIdx.x * blockDim.x + threadIdx.x;
    float x[DIM];
    const float4* v4 = (const float4*)(vecs + (size_t)v * DIM);
#pragma unroll
    for (int i = 0; i < DIM / 4; ++i) {
        float4 t = v4[i];
        x[4 * i + 0] = t.x;
        x[4 * i + 1] = t.y;
        x[4 * i + 2] = t.z;
        x[4 * i + 3] = t.w;
    }

    int   best      = 0;
    float bestScore = 3.4e38f;

    for (int c = 0; c < NLIST; c += 2) {
        const float* c0 = cents + (size_t)c * DIM;
        const float* c1 = c0 + DIM;
        float a0 = 0.f, a1 = 0.f, a2 = 0.f, a3 = 0.f;
        float b0 = 0.f, b1 = 0.f, b2 = 0.f, b3 = 0.f;
#pragma unroll
        for (int k = 0; k < DIM; k += 4) {
            a0 = fmaf(x[k + 0], c0[k + 0], a0);
            a1 = fmaf(x[k + 1], c0[k + 1], a1);
            a2 = fmaf(x[k + 2], c0[k + 2], a2);
            a3 = fmaf(x[k + 3], c0[k + 3], a3);
            b0 = fmaf(x[k + 0], c1[k + 0], b0);
            b1 = fmaf(x[k + 1], c1[k + 1], b1);
            b2 = fmaf(x[k + 2], c1[k + 2], b2);
            b3 = fmaf(x[k + 3], c1[k + 3], b3);
        }
        float dot0 = (a0 + a1) + (a2 + a3);
        float dot1 = (b0 + b1) + (b2 + b3);
        float s0 = fmaf(-2.f, dot0, csq[c]);
        float s1 = fmaf(-2.f, dot1, csq[c + 1]);
        // ascending c + strict < == argmin first-min tie rule
        if (s0 < bestScore) { bestScore = s0; best = c; }
        if (s1 < bestScore) { bestScore = s1; best = c + 1; }
    }
    assign[v] = best;
}

// ---------------------------------------------------------------------------
// Kernel 3: out[v] = centroids[assign[v]], coalesced float4 writes.
// 16 float4 chunks per row; consecutive threads write consecutive float4s.
// ---------------------------------------------------------------------------
__global__ __launch_bounds__(256) void gather_kernel(const float* __restrict__ cents,
                                                     const int* __restrict__ assign,
                                                     float* __restrict__ out) {
    int gid = blockIdx.x * blockDim.x + threadIdx.x;   // one float4 per thread
    int v = gid >> 4;
    int e = gid & 15;
    int idx = assign[v];
    ((float4*)out)[(size_t)gid] = ((const float4*)cents)[(size_t)idx * (DIM / 4) + e];
}

extern "C" void kernel_launch(void* const* d_in, const int* in_sizes, int n_in,
                              void* d_out, int out_size, void* d_ws, size_t ws_size,
                              hipStream_t stream) {
    const float* vecs  = (const float*)d_in[0];
    const float* cents = (const float*)d_in[1];
    float*       out   = (float*)d_out;

    float* csq    = (float*)d_ws;                       // 1024 floats
    int*   assign = (int*)((char*)d_ws + 4096);         // NVEC ints

    csq_kernel<<<dim3((NLIST + 255) / 256), dim3(256), 0, stream>>>(cents, csq);
    assign_kernel<<<dim3(NVEC / 256), dim3(256), 0, stream>>>(vecs, cents, csq, assign);
    gather_kernel<<<dim3(NVEC * (DIM / 4) / 256), dim3(256), 0, stream>>>(cents, assign, out);
}

// Round 2
// 320.412 us; speedup vs baseline: 2.2446x; 2.2446x over previous
//
#include <hip/hip_runtime.h>
#include <hip/hip_bf16.h>

#define NVEC   262144
#define NLIST  1024
#define DIM    64
#define NCHUNK 64          // 64 chunks x 16 centroids
#define DELTA  0.03f       // rescue threshold; approx d2 error bound ~4e-4

typedef __attribute__((ext_vector_type(8))) short bf16x8;
typedef __attribute__((ext_vector_type(4))) float f32x4;

__device__ __forceinline__ unsigned short bf_rne(float f) {
    unsigned int u = __float_as_uint(f);
    u += 0x7fffu + ((u >> 16) & 1u);
    return (unsigned short)(u >> 16);
}
__device__ __forceinline__ float bf_up(unsigned short s) {
    return __uint_as_float(((unsigned int)s) << 16);
}

// ---------------------------------------------------------------------------
// K0: csq (exact fp32, same chain as round-0), zero rescue counter, and build
// Cmat: per chunk (16 cents) a 4096B image; row m = 16 blocks of 16B
// (8 bf16): logical block j<8 = hi elems j*8..+7, j>=8 = lo elems (j-8)*8..+7,
// stored at position (j+m)&15  (bank swizzle so frag ds_read_b128 is even).
// ---------------------------------------------------------------------------
__global__ __launch_bounds__(256) void prep_kernel(const float* __restrict__ cents,
                                                   float* __restrict__ csq,
                                                   int* __restrict__ counter,
                                                   unsigned short* __restrict__ cmat) {
    int gid = blockIdx.x * 256 + threadIdx.x;
    if (gid == 0) *counter = 0;
    if (gid < NLIST) {
        const float4* p = (const float4*)(cents + (size_t)gid * DIM);
        float s = 0.f;
#pragma unroll
        for (int i = 0; i < DIM / 4; ++i) {
            float4 t = p[i];
            s += t.x * t.x + t.y * t.y + t.z * t.z + t.w * t.w;
        }
        csq[gid] = s;
    }
    int c = gid >> 4;          // centroid 0..1023
    int j = gid & 15;          // logical block
    int chunk = c >> 4, m = c & 15;
    const float* src = cents + (size_t)c * DIM + (j & 7) * 8;
    unsigned short o[8];
#pragma unroll
    for (int i = 0; i < 8; ++i) {
        float v = src[i];
        unsigned short h = bf_rne(v);
        o[i] = (j < 8) ? h : bf_rne(v - bf_up(h));
    }
    unsigned short* dst = cmat + chunk * 2048 + m * 128 + (((j + m) & 15) * 8);
#pragma unroll
    for (int i = 0; i < 8; ++i) dst[i] = o[i];
}

// ---------------------------------------------------------------------------
// K1: MFMA assign. Workgroup = 4 waves; wave owns 64 vecs (4 col-tiles of 16).
// D[cent][vec] = A(cent frags from LDS) x B(vec frags in VGPRs).
// score = csq - 2*dot; per-lane top-2 across its 256 cents, quad-merge at end.
// ---------------------------------------------------------------------------
__global__ __launch_bounds__(256, 4) void assign_mfma(const float* __restrict__ vecs,
                                                      const unsigned short* __restrict__ cmat,
                                                      const float* __restrict__ csq_g,
                                                      int* __restrict__ assign,
                                                      int* __restrict__ counter,
                                                      int* __restrict__ rescue) {
    __shared__ __align__(16) float csq_lds[NLIST];
    __shared__ __align__(16) unsigned short chunkbuf[2][2048];

    const int tid  = threadIdx.x;
    const int lane = tid & 63;
    const int wave = tid >> 6;
    const int n    = lane & 15;   // vec-in-tile for B, cent-in-chunk for A
    const int q    = lane >> 4;

    ((float4*)csq_lds)[tid] = ((const float4*)csq_g)[tid];

    const int vbase = blockIdx.x * 256 + wave * 64;

    // B fragments: x_hi/x_lo, 2 K-blocks of 32 each, 4 tiles. 64 VGPRs.
    bf16x8 xhi[4][2], xlo[4][2];
#pragma unroll
    for (int t = 0; t < 4; ++t) {
        const float* vp = vecs + (size_t)(vbase + t * 16 + n) * DIM + q * 8;
#pragma unroll
        for (int kb = 0; kb < 2; ++kb) {
            float4 f0 = *(const float4*)(vp + kb * 32);
            float4 f1 = *(const float4*)(vp + kb * 32 + 4);
            float vv[8] = {f0.x, f0.y, f0.z, f0.w, f1.x, f1.y, f1.z, f1.w};
#pragma unroll
            for (int i = 0; i < 8; ++i) {
                unsigned short h = bf_rne(vv[i]);
                xhi[t][kb][i] = (short)h;
                xlo[t][kb][i] = (short)bf_rne(vv[i] - bf_up(h));
            }
        }
    }

    // stage chunk 0 (4096B = 4 waves x 64 lanes x 16B, direct-to-LDS)
    {
        const unsigned short* g = cmat + wave * 512 + lane * 8;
        __builtin_amdgcn_global_load_lds(
            (const __attribute__((address_space(1))) void*)g,
            (__attribute__((address_space(3))) void*)(&chunkbuf[0][wave * 512]),
            16, 0, 0);
    }

    const float FMAX = 3.0e38f;
    float min1[4] = {FMAX, FMAX, FMAX, FMAX};
    float min2[4] = {FMAX, FMAX, FMAX, FMAX};
    int   idx1[4] = {0, 0, 0, 0};
    int   idx2[4] = {0, 0, 0, 0};

    for (int c = 0; c < NCHUNK; ++c) {
        __syncthreads();   // publishes buf[c&1]; drains in-flight stage
        if (c + 1 < NCHUNK) {
            const unsigned short* g = cmat + (c + 1) * 2048 + wave * 512 + lane * 8;
            __builtin_amdgcn_global_load_lds(
                (const __attribute__((address_space(1))) void*)g,
                (__attribute__((address_space(3))) void*)(&chunkbuf[(c + 1) & 1][wave * 512]),
                16, 0, 0);
        }
        const unsigned short* B = chunkbuf[c & 1];
        // A frags: logical blocks q, 4+q (hi), 8+q, 12+q (lo), de-swizzled
        bf16x8 a0 = *(const bf16x8*)(B + n * 128 + (((q      + n) & 15) * 8));
        bf16x8 a1 = *(const bf16x8*)(B + n * 128 + (((4 + q  + n) & 15) * 8));
        bf16x8 a2 = *(const bf16x8*)(B + n * 128 + (((8 + q  + n) & 15) * 8));
        bf16x8 a3 = *(const bf16x8*)(B + n * 128 + (((12 + q + n) & 15) * 8));
        float4 cs = *(const float4*)(csq_lds + c * 16 + q * 4);

        f32x4 acc[4];
#pragma unroll
        for (int t = 0; t < 4; ++t) acc[t] = (f32x4){0.f, 0.f, 0.f, 0.f};
        // dot = x_hi.c_hi + x_lo.c_hi + x_hi.c_lo  (4 indep chains)
#pragma unroll
        for (int t = 0; t < 4; ++t) acc[t] = __builtin_amdgcn_mfma_f32_16x16x32_bf16(a0, xhi[t][0], acc[t], 0, 0, 0);
#pragma unroll
        for (int t = 0; t < 4; ++t) acc[t] = __builtin_amdgcn_mfma_f32_16x16x32_bf16(a1, xhi[t][1], acc[t], 0, 0, 0);
#pragma unroll
        for (int t = 0; t < 4; ++t) acc[t] = __builtin_amdgcn_mfma_f32_16x16x32_bf16(a2, xhi[t][0], acc[t], 0, 0, 0);
#pragma unroll
        for (int t = 0; t < 4; ++t) acc[t] = __builtin_amdgcn_mfma_f32_16x16x32_bf16(a3, xhi[t][1], acc[t], 0, 0, 0);
#pragma unroll
        for (int t = 0; t < 4; ++t) acc[t] = __builtin_amdgcn_mfma_f32_16x16x32_bf16(a0, xlo[t][0], acc[t], 0, 0, 0);
#pragma unroll
        for (int t = 0; t < 4; ++t) acc[t] = __builtin_amdgcn_mfma_f32_16x16x32_bf16(a1, xlo[t][1], acc[t], 0, 0, 0);

        const int bg = c * 16 + q * 4;
        float csr[4] = {cs.x, cs.y, cs.z, cs.w};
#pragma unroll
        for (int t = 0; t < 4; ++t) {
#pragma unroll
            for (int r = 0; r < 4; ++r) {
                float s = fmaf(-2.0f, acc[t][r], csr[r]);
                int gi = bg + r;                  // ascending per lane -> strict <
                bool b1 = s < min1[t];
                bool b2 = s < min2[t];
                min2[t] = b1 ? min1[t] : (b2 ? s : min2[t]);
                idx2[t] = b1 ? idx1[t] : (b2 ? gi : idx2[t]);
                min1[t] = b1 ? s : min1[t];
                idx1[t] = b1 ? gi : idx1[t];
            }
        }
    }

    // merge top-2 across the 4 quads sharing a vec-col, tie -> lower idx
#pragma unroll
    for (int t = 0; t < 4; ++t) {
        for (int off = 16; off <= 32; off <<= 1) {
            float om1 = __shfl_xor(min1[t], off, 64);
            int   oi1 = __shfl_xor(idx1[t], off, 64);
            float om2 = __shfl_xor(min2[t], off, 64);
            int   oi2 = __shfl_xor(idx2[t], off, 64);
            bool aw = (min1[t] < om1) || (min1[t] == om1 && idx1[t] < oi1);
            float ca = aw ? min2[t] : om2;   int cia = aw ? idx2[t] : oi2;
            float cb = aw ? om1     : min1[t]; int cib = aw ? oi1   : idx1[t];
            float nm1 = aw ? min1[t] : om1;  int ni1 = aw ? idx1[t] : oi1;
            bool bw = (ca < cb) || (ca == cb && cia < cib);
            min1[t] = nm1;  idx1[t] = ni1;
            min2[t] = bw ? ca : cb;
            idx2[t] = bw ? cia : cib;
        }
        if (lane < 16) {
            int vec = vbase + t * 16 + lane;
            assign[vec] = idx1[t];
            if (min2[t] - min1[t] < DELTA) {
                int pos = atomicAdd(counter, 1);
                rescue[pos] = vec;
            }
        }
    }
}

// ---------------------------------------------------------------------------
// K2: exact fp32 rescue, one wave per flagged row; 16 cents/lane (stride 64),
// round-0 fmaf chain; cross-lane argmin with tie -> lower idx.
// ---------------------------------------------------------------------------
__global__ __launch_bounds__(256) void rescue_kernel(const float* __restrict__ vecs,
                                                     const float* __restrict__ cents,
                                                     const float* __restrict__ csq,
                                                     const int* __restrict__ counter,
                                                     const int* __restrict__ list,
                                                     int* __restrict__ assign) {
    int nflag = *counter;
    int gwave = (blockIdx.x * 256 + threadIdx.x) >> 6;
    int lane  = threadIdx.x & 63;
    int nw    = gridDim.x * 4;
    for (int i = gwave; i < nflag; i += nw) {
        int v = list[i];
        float x[DIM];
        const float4* vp = (const float4*)(vecs + (size_t)v * DIM);
#pragma unroll
        for (int k = 0; k < DIM / 4; ++k) {
            float4 t = vp[k];
            x[4 * k] = t.x; x[4 * k + 1] = t.y; x[4 * k + 2] = t.z; x[4 * k + 3] = t.w;
        }
        float best = 3.0e38f; int bi = 0;
        for (int j = 0; j < 16; ++j) {
            int cc = j * 64 + lane;                 // ascending per lane
            const float* cp = cents + (size_t)cc * DIM;
            float a0 = 0.f, a1 = 0.f, a2 = 0.f, a3 = 0.f;
#pragma unroll
            for (int k = 0; k < DIM; k += 4) {
                a0 = fmaf(x[k + 0], cp[k + 0], a0);
                a1 = fmaf(x[k + 1], cp[k + 1], a1);
                a2 = fmaf(x[k + 2], cp[k + 2], a2);
                a3 = fmaf(x[k + 3], cp[k + 3], a3);
            }
            float dot = (a0 + a1) + (a2 + a3);
            float s = fmaf(-2.f, dot, csq[cc]);
            if (s < best) { best = s; bi = cc; }
        }
        for (int off = 1; off < 64; off <<= 1) {
            float os = __shfl_xor(best, off, 64);
            int   oi = __shfl_xor(bi, off, 64);
            if (os < best || (os == best && oi < bi)) { best = os; bi = oi; }
        }
        if (lane == 0) assign[v] = bi;
    }
}

// ---------------------------------------------------------------------------
// K3: gather, coalesced float4
// ---------------------------------------------------------------------------
__global__ __launch_bounds__(256) void gather_kernel(const float* __restrict__ cents,
                                                     const int* __restrict__ assign,
                                                     float* __restrict__ out) {
    int gid = blockIdx.x * blockDim.x + threadIdx.x;
    int v = gid >> 4;
    int e = gid & 15;
    int idx = assign[v];
    ((float4*)out)[(size_t)gid] = ((const float4*)cents)[(size_t)idx * (DIM / 4) + e];
}

extern "C" void kernel_launch(void* const* d_in, const int* in_sizes, int n_in,
                              void* d_out, int out_size, void* d_ws, size_t ws_size,
                              hipStream_t stream) {
    const float* vecs  = (const float*)d_in[0];
    const float* cents = (const float*)d_in[1];
    float*       out   = (float*)d_out;

    // ws layout (all 16B aligned)
    float*          csq     = (float*)d_ws;                                   //   4096 B
    int*            counter = (int*)((char*)d_ws + 4096);                     //    256 B
    unsigned short* cmat    = (unsigned short*)((char*)d_ws + 4352);          // 262144 B
    int*            list    = (int*)((char*)d_ws + 266496);                   //   1 MB
    int*            assign  = (int*)((char*)d_ws + 1315072);                  //   1 MB

    prep_kernel<<<dim3(64), dim3(256), 0, stream>>>(cents, csq, counter, cmat);
    assign_mfma<<<dim3(1024), dim3(256), 0, stream>>>(vecs, cmat, csq, assign, counter, list);
    rescue_kernel<<<dim3(256), dim3(256), 0, stream>>>(vecs, cents, csq, counter, list, assign);
    gather_kernel<<<dim3(NVEC * (DIM / 4) / 256), dim3(256), 0, stream>>>(cents, assign, out);
}